// Round 6
// baseline (247.665 us; speedup 1.0000x reference)
//
#include <hip/hip_runtime.h>

// SSIM loss, fused separable, STREAMING column-band kernel.
// B*C=48 images of 512x512 fp32, 11x11 Gaussian window, separable via
// row-sums (w1[i] = sum_j window[i][j]; sum(w1)==1).
//
// Round-6: round-5 (148 us) had no saturated pipe (VALU 50%, LDS ok, HBM 12%)
// at 27% occupancy -> residency/ramp-bound: 12288 short blocks, ~2 resident
// per CU. Round 6: 768 long blocks (48 img x 16 bands of 32 cols, exactly
// 3 blocks/CU), each streams 17 iters x 32 rows with a 42-row x 32-col x
// 5-field h-blurred ring (linear buffer + 10-row halo copy). Vertical halo
// rows are computed once (24% h-pass savings vs round 5) and v-pass LDS row
// offsets are compile-time constants.
// SROA rules from rounds 2-4: no local array ever passed to a function;
// float4 components extracted BY NAME; constant indices only.
// Tail: fire-and-forget f64 atomic into 128 slots + 1-wave finalize kernel
// (round-4's fence+returning-counter tail cost ~460 us -- never again).

#define WSZ   11
#define RAD   5
#define BAND  32          // cols per block
#define BUFR  42          // buffered h-blurred rows: 32 new + 10 halo
#define BLOCK 256
#define NWAVE (BLOCK/64)
#define NSLOT 128
#define NITER 17          // 16 iters cover 512 rows; +1 flush (rows >=512 = 0)

// Horizontal 11-tap conv of src[0..13] -> 4 outputs -> one b128 LDS store.
// Pure textual expansion: src stays SROA-able (constant indices only).
#define HCONV_STORE(src, f)                                              \
    {                                                                    \
        float s0 = 0.f, s1 = 0.f, s2 = 0.f, s3 = 0.f;                    \
        _Pragma("unroll")                                                \
        for (int k = 0; k < WSZ; ++k) {                                  \
            const float wk = w[k];                                       \
            s0 += wk * src[k];                                           \
            s1 += wk * src[k + 1];                                       \
            s2 += wk * src[k + 2];                                       \
            s3 += wk * src[k + 3];                                       \
        }                                                                \
        *reinterpret_cast<float4*>(&buf[f][10 + r][4 * g]) =             \
            make_float4(s0, s1, s2, s3);                                 \
    }

// Vertical 11-tap conv over buffer rows [8*gr, 8*gr+17] of field f -> res[8].
#define VCONV(f, res)                                                    \
    {                                                                    \
        float col[18];                                                   \
        _Pragma("unroll")                                                \
        for (int k = 0; k < 18; ++k) col[k] = buf[f][rb + k][c];         \
        _Pragma("unroll")                                                \
        for (int j = 0; j < 8; ++j) {                                    \
            float s = 0.f;                                               \
            _Pragma("unroll")                                            \
            for (int k = 0; k < WSZ; ++k) s += w[k] * col[j + k];        \
            res[j] = s;                                                  \
        }                                                                \
    }

__global__ __launch_bounds__(BLOCK) void ssim_stream_kernel(
    const float* __restrict__ pred,
    const float* __restrict__ target,
    const float* __restrict__ window,
    double* __restrict__ acc,          // NSLOT slots
    int H, int W)
{
    __shared__ float buf[5][BUFR][BAND];   // h-blurred: mu1s, mu2s, pp, pt, tt
    __shared__ float w1s[WSZ];
    __shared__ float wavesum[NWAVE];

    const int t = threadIdx.x;

    // Recover separable 1D window (row sums of the 2D window).
    if (t < WSZ) {
        float s = 0.f;
        #pragma unroll
        for (int j = 0; j < WSZ; ++j) s += window[t * WSZ + j];
        w1s[t] = s;
    }

    const int img  = blockIdx.x >> 4;      // 48 images
    const int band = blockIdx.x & 15;      // 16 bands of 32 cols
    const int col0 = band * BAND - RAD;    // leftmost col the conv touches

    const float* __restrict__ p = pred   + (size_t)img * H * W;
    const float* __restrict__ q = target + (size_t)img * H * W;

    // Zero the top halo (rows -10..-1 of the image).
    for (int l = t; l < 5 * 10 * BAND; l += BLOCK) {
        const int f = l / (10 * BAND), rem = l - f * (10 * BAND);
        buf[f][rem / BAND][rem % BAND] = 0.f;
    }
    __syncthreads();

    float w[WSZ];
    #pragma unroll
    for (int k = 0; k < WSZ; ++k) w[k] = w1s[k];

    const bool interior = (band > 0) && (band < 15);

    // h-pass unit: (row r of 32, col-group g of 4); exactly 256 units.
    const int hr = t >> 3, hg = t & 7;
    // v-pass unit: (col c of 32, group gr of 8 out-rows); 128 units.
    const int c  = t & 31;
    const int gr = t >> 5;                 // 0..7, only 0..3 used
    const int rb = gr * 8;                 // buffer row base (constant offs)

    float local = 0.f;

    for (int i = 0; i < NITER; ++i) {
        // ---- halo copy: buf[f][32+j][*] -> buf[f][j][*]  (j=0..9) ----
        if (i > 0) {
            for (int idx = t; idx < 400; idx += BLOCK) {   // 400 float4 chunks
                const int f = idx / 80, rem = idx - f * 80;
                const int j = rem >> 3, k4 = (rem & 7) * 4;
                const float4 v = *reinterpret_cast<const float4*>(&buf[f][32 + j][k4]);
                *reinterpret_cast<float4*>(&buf[f][j][k4]) = v;
            }
            __syncthreads();
        }

        // ---- horizontal pass: rows rr = 32*i + hr into buf rows 10..41 ----
        {
            const int r = hr, g = hg;
            const int rr = 32 * i + r;
            const bool rok = rr < H;       // rows >= 512 (flush iter) are zero

            float pv[14], tv[14];          // cols col0+4g .. col0+4g+13
            if (interior && rok) {
                const float4* __restrict__ prow =
                    reinterpret_cast<const float4*>(p + (size_t)rr * W);
                const float4* __restrict__ qrow =
                    reinterpret_cast<const float4*>(q + (size_t)rr * W);
                const int b = band * 8 + g - 2;    // (band*32+4g-8)/4, aligned
                const float4 P0 = prow[b],     P1 = prow[b + 1], P2 = prow[b + 2],
                             P3 = prow[b + 3], P4 = prow[b + 4];
                const float4 Q0 = qrow[b],     Q1 = qrow[b + 1], Q2 = qrow[b + 2],
                             Q3 = qrow[b + 3], Q4 = qrow[b + 4];
                pv[0]  = P0.w;
                pv[1]  = P1.x; pv[2]  = P1.y; pv[3]  = P1.z; pv[4]  = P1.w;
                pv[5]  = P2.x; pv[6]  = P2.y; pv[7]  = P2.z; pv[8]  = P2.w;
                pv[9]  = P3.x; pv[10] = P3.y; pv[11] = P3.z; pv[12] = P3.w;
                pv[13] = P4.x;
                tv[0]  = Q0.w;
                tv[1]  = Q1.x; tv[2]  = Q1.y; tv[3]  = Q1.z; tv[4]  = Q1.w;
                tv[5]  = Q2.x; tv[6]  = Q2.y; tv[7]  = Q2.z; tv[8]  = Q2.w;
                tv[9]  = Q3.x; tv[10] = Q3.y; tv[11] = Q3.z; tv[12] = Q3.w;
                tv[13] = Q4.x;
            } else {
                const int cb = col0 + 4 * g;
                #pragma unroll
                for (int ii = 0; ii < 14; ++ii) {
                    const int gc = cb + ii;
                    const bool ok = rok && ((unsigned)gc < (unsigned)W);
                    const size_t idx = (size_t)rr * W + gc;
                    pv[ii] = ok ? p[idx] : 0.f;
                    tv[ii] = ok ? q[idx] : 0.f;
                }
            }

            HCONV_STORE(pv, 0)                     // mu1 source
            HCONV_STORE(tv, 1)                     // mu2 source

            float prod[14];
            #pragma unroll
            for (int ii = 0; ii < 14; ++ii) prod[ii] = pv[ii] * tv[ii];
            HCONV_STORE(prod, 3)                   // p*t
            #pragma unroll
            for (int ii = 0; ii < 14; ++ii) prod[ii] = pv[ii] * pv[ii];
            HCONV_STORE(prod, 2)                   // p^2
            #pragma unroll
            for (int ii = 0; ii < 14; ++ii) prod[ii] = tv[ii] * tv[ii];
            HCONV_STORE(prod, 4)                   // t^2
        }
        __syncthreads();

        // ---- vertical pass: out rows ro = 32*i - 5 + 8*gr + j ----
        if (t < 128) {
            float a1[8], a2[8], a11[8], a12[8], a22[8];
            VCONV(0, a1)
            VCONV(1, a2)
            VCONV(2, a11)
            VCONV(3, a12)
            VCONV(4, a22)

            const float C1  = 1e-4f;   // (0.01*1)^2
            const float C2  = 9e-4f;   // (0.03*1)^2
            const float EPS = 1e-8f;
            const int ro0 = 32 * i - RAD + rb;
            #pragma unroll
            for (int j = 0; j < 8; ++j) {
                if ((unsigned)(ro0 + j) < (unsigned)H) {
                    const float m1 = a1[j], m2 = a2[j];
                    const float m1sq = m1 * m1, m2sq = m2 * m2, m12 = m1 * m2;
                    const float v1 = a11[j] - m1sq;
                    const float v2 = a22[j] - m2sq;
                    const float cv = a12[j] - m12;
                    const float num = (2.f * m12 + C1) * (2.f * cv + C2);
                    const float den = (m1sq + m2sq + C1) * (v1 + v2 + C2) + EPS;
                    local += num / den;
                }
            }
        }
        __syncthreads();   // before next iter's halo copy overwrites rows 0..9
    }

    // Wave shuffle reduce, cross-wave via LDS, one fire-and-forget f64
    // atomic per block into one of 128 slots.
    #pragma unroll
    for (int off = 32; off > 0; off >>= 1)
        local += __shfl_down(local, off, 64);
    const int lane = t & 63, wid = t >> 6;
    if (lane == 0) wavesum[wid] = local;
    __syncthreads();
    if (t == 0) {
        float s = 0.f;
        #pragma unroll
        for (int wv = 0; wv < NWAVE; ++wv) s += wavesum[wv];
        atomicAdd(&acc[blockIdx.x & (NSLOT - 1)], (double)s);
    }
}

__global__ void ssim_finalize_kernel(const double* __restrict__ acc,
                                     float* __restrict__ out, double invN)
{
    const int l = threadIdx.x;
    double s = acc[l] + acc[l + 64];
    #pragma unroll
    for (int off = 32; off > 0; off >>= 1)
        s += __shfl_down(s, off, 64);
    if (l == 0) out[0] = (float)(1.0 - s * invN);
}

extern "C" void kernel_launch(void* const* d_in, const int* in_sizes, int n_in,
                              void* d_out, int out_size, void* d_ws, size_t ws_size,
                              hipStream_t stream)
{
    const float* pred   = (const float*)d_in[0];
    const float* target = (const float*)d_in[1];
    const float* window = (const float*)d_in[2];
    float*  out = (float*)d_out;
    double* acc = (double*)d_ws;

    const int B = 16, C = 3, H = 512, W = 512;
    const int n_img = B * C;
    const int blocks = n_img * (W / BAND);     // 48 * 16 = 768

    // ws is re-poisoned 0xAA before every timed launch: zero the slots.
    hipMemsetAsync(d_ws, 0, NSLOT * sizeof(double), stream);

    ssim_stream_kernel<<<blocks, BLOCK, 0, stream>>>(
        pred, target, window, acc, H, W);

    const double invN = 1.0 / ((double)n_img * H * W);
    ssim_finalize_kernel<<<1, 64, 0, stream>>>(acc, out, invN);
}